// Round 2
// baseline (426.967 us; speedup 1.0000x reference)
//
#include <hip/hip_runtime.h>
#include <hip/hip_bf16.h>

#define B_    32
#define S_    4096
#define CIN_  7
#define NF_   35      // 5 * CIN
#define D_    512
#define WIN_  24
#define K3_   105     // NF * 3
#define QN_   66      // tap positions per block: s0-1 .. s0+64

// ---------------------------------------------------------------------------
// Fused kernel: rolling stats (window=24, front-clamped) into LDS, then
// circular conv1d k=3, 35 -> 512 channels, directly to out[b][s][d].
//
// Block: 256 threads = 256 consecutive d-channels (blockIdx.y picks half of D),
// covering 64 s-positions (blockIdx.x) for one batch b (blockIdx.z).
// No global workspace: stats live in 9.2 KB LDS, weights in VGPRs.
// ---------------------------------------------------------------------------
__global__ __launch_bounds__(256, 2) void fused_stats_conv_kernel(
    const float* __restrict__ x, const float* __restrict__ W,
    const float* __restrict__ bias, float* __restrict__ out)
{
    __shared__ float sfeats[NF_ * QN_];     // [i][q], i=feature row, q=tap pos

    const int tid = threadIdx.x;
    const int s0  = blockIdx.x * 64;        // block's first output s
    const int b   = blockIdx.z;

    // ---------------- Phase 1: stats for q = 0..65 (pos = s0-1+q, circular) --
    const float* xb = x + (size_t)b * S_ * CIN_;
    for (int t = tid; t < QN_ * CIN_; t += 256) {
        const int q = t / CIN_;             // 0..65
        const int f = t - q * CIN_;         // 0..6
        int p = s0 - 1 + q;                 // circular tap position
        const int sm = p < 0 ? p + S_ : (p >= S_ ? p - S_ : p);

        float v[WIN_];
        #pragma unroll
        for (int j = 0; j < WIN_; ++j) {
            int sc = sm - (WIN_ - 1) + j;   // front-clamped window
            sc = sc < 0 ? 0 : sc;
            v[j] = xb[(size_t)sc * CIN_ + f];
        }
        float sum = 0.f, mx = v[0], mn = v[0];
        #pragma unroll
        for (int j = 0; j < WIN_; ++j) {
            sum += v[j];
            mx = fmaxf(mx, v[j]);
            mn = fminf(mn, v[j]);
        }
        const float mean = sum * (1.0f / WIN_);
        float var = 0.f;
        #pragma unroll
        for (int j = 0; j < WIN_; ++j) {
            const float dv = v[j] - mean;
            var = fmaf(dv, dv, var);
        }
        var *= (1.0f / (WIN_ - 1));
        const float sd = sqrtf(var + 1e-12f);

        sfeats[(f        ) * QN_ + q] = v[WIN_ - 1];  // x
        sfeats[(f + 7    ) * QN_ + q] = mean;
        sfeats[(f + 14   ) * QN_ + q] = mx;
        sfeats[(f + 21   ) * QN_ + q] = mn;
        sfeats[(f + 28   ) * QN_ + q] = sd;
    }
    __syncthreads();

    // ---------------- Phase 2: conv over d = blockIdx.y*256 + tid -----------
    const int d = blockIdx.y * 256 + tid;
    const float bd = bias[d];

    // Preload this channel's 105 weights (420 contiguous bytes -> L1-hot).
    float w[K3_];
    const float* Wd = W + (size_t)d * K3_;
    #pragma unroll
    for (int kappa = 0; kappa < K3_; ++kappa) w[kappa] = Wd[kappa];

    #pragma unroll 1
    for (int chunk = 0; chunk < 4; ++chunk) {
        float acc[16];
        #pragma unroll
        for (int j = 0; j < 16; ++j) acc[j] = bd;

        #pragma unroll
        for (int i = 0; i < NF_; ++i) {
            // taps q = chunk*16 + t, t = 0..17  (wave-uniform LDS broadcast)
            float a[18];
            #pragma unroll
            for (int t = 0; t < 18; ++t)
                a[t] = sfeats[i * QN_ + chunk * 16 + t];
            #pragma unroll
            for (int kk = 0; kk < 3; ++kk) {
                const float wv = w[i * 3 + kk];
                #pragma unroll
                for (int j = 0; j < 16; ++j)
                    acc[j] = fmaf(wv, a[j + kk], acc[j]);
            }
        }

        float* ob = out + ((size_t)b * S_ + s0 + chunk * 16) * D_ + d;
        #pragma unroll
        for (int j = 0; j < 16; ++j)
            ob[(size_t)j * D_] = acc[j];
    }
}

// ---------------------------------------------------------------------------
extern "C" void kernel_launch(void* const* d_in, const int* in_sizes, int n_in,
                              void* d_out, int out_size, void* d_ws, size_t ws_size,
                              hipStream_t stream) {
    const float* x      = (const float*)d_in[0];   // (32, 4096, 7)
    // d_in[1] = x_mark: unused by the reference
    const float* W_conv = (const float*)d_in[2];   // (512, 35, 3)
    const float* b_conv = (const float*)d_in[3];   // (512,)
    float* out = (float*)d_out;                    // (32, 4096, 512)

    fused_stats_conv_kernel<<<dim3(S_ / 64, D_ / 256, B_), dim3(256), 0, stream>>>(
        x, W_conv, b_conv, out);
}

// Round 3
// 293.431 us; speedup vs baseline: 1.4551x; 1.4551x over previous
//
#include <hip/hip_runtime.h>

#define B_    32
#define S_    4096
#define CIN_  7
#define NF_   35      // 5 * CIN
#define D_    512
#define WIN_  24
#define K3_   105     // NF * 3 (GEMM K)
#define P_    120     // LDS A row stride in bf16 elems (mult of 8, not pow2)
#define QN_   66      // tap positions per s-tile: s0-1 .. s0+64

typedef __attribute__((ext_vector_type(8))) short short8;   // 8 x bf16 (4 VGPR)
typedef __attribute__((ext_vector_type(4))) float float4_;  // MFMA C/D

__device__ __forceinline__ unsigned short f2bf(float f) {
    unsigned int u = __builtin_bit_cast(unsigned int, f);
    u += 0x7FFFu + ((u >> 16) & 1u);          // RNE to bf16
    return (unsigned short)(u >> 16);
}

// ---------------------------------------------------------------------------
// Pack W (512, 35, 3) fp32 -> bf16 B-fragments, fragment-linear:
//   slot(nsub 0..31, kstep 0..3, lane 0..63) holds 8 bf16:
//     B[k = kstep*32 + (lane>>4)*8 + j][d = nsub*16 + (lane&15)],  j=0..7
//   (i.e. Bt[d][k..k+7], zero-padded for k >= 105)
// GEMM waves then load B-frags with fully lane-coalesced dwordx4.
// ---------------------------------------------------------------------------
__global__ __launch_bounds__(256) void pack_w_kernel(
    const float* __restrict__ W, short* __restrict__ Bf)
{
    const int slot = blockIdx.x * 256 + threadIdx.x;   // 0..8191
    if (slot >= 32 * 4 * 64) return;
    const int l     = slot & 63;
    const int kstep = (slot >> 6) & 3;
    const int nsub  = slot >> 8;
    const int d  = nsub * 16 + (l & 15);
    const int kb = kstep * 32 + (l >> 4) * 8;

    short8 v;
    #pragma unroll
    for (int j = 0; j < 8; ++j) {
        const int kappa = kb + j;
        v[j] = (kappa < K3_) ? (short)f2bf(W[(size_t)d * K3_ + kappa]) : (short)0;
    }
    *(short8*)(Bf + (size_t)slot * 8) = v;
}

// ---------------------------------------------------------------------------
// Fused kernel: rolling stats -> bf16 A-tile in LDS -> MFMA GEMM -> out.
// Block: 512 threads = 8 waves; blockIdx = (s-tile of 64, b).
// Wave w covers d = w*64 .. w*64+63 as a 4x4 grid of 16x16x32 bf16 MFMAs.
// ---------------------------------------------------------------------------
template <bool USE_WS>
__global__ __launch_bounds__(512, 4) void fused_mfma_kernel(
    const float* __restrict__ x, const float* __restrict__ W,
    const short* __restrict__ Bf, const float* __restrict__ bias,
    float* __restrict__ out)
{
    __shared__ short sA[64 * P_];            // A[m=0..63][kappa], bf16 bits

    const int tid = threadIdx.x;
    const int s0  = blockIdx.x * 64;
    const int b   = blockIdx.y;

    // ---- Phase 1: stats for taps q=0..65 (s = s0-1+q circular), to LDS ----
    if (tid < QN_ * CIN_) {
        const int q = tid / CIN_;
        const int f = tid - q * CIN_;
        int p = s0 - 1 + q;
        const int sm = p < 0 ? p + S_ : (p >= S_ ? p - S_ : p);
        const float* xb = x + (size_t)b * S_ * CIN_ + f;

        float v[WIN_];
        #pragma unroll
        for (int j = 0; j < WIN_; ++j) {
            int sc = sm - (WIN_ - 1) + j;    // front-clamped window
            sc = sc < 0 ? 0 : sc;
            v[j] = xb[(size_t)sc * CIN_];
        }
        float sum = 0.f, mx = v[0], mn = v[0];
        #pragma unroll
        for (int j = 0; j < WIN_; ++j) {
            sum += v[j];
            mx = fmaxf(mx, v[j]);
            mn = fminf(mn, v[j]);
        }
        const float mean = sum * (1.0f / WIN_);
        float var = 0.f;
        #pragma unroll
        for (int j = 0; j < WIN_; ++j) {
            const float dv = v[j] - mean;
            var = fmaf(dv, dv, var);
        }
        const float sd = sqrtf(var * (1.0f / (WIN_ - 1)) + 1e-12f);

        const float vals[5] = { v[WIN_ - 1], mean, mx, mn, sd };
        // A[m][kappa=i*3+k] = tap[i][q] with m = q - k
        #pragma unroll
        for (int k = 0; k < 3; ++k) {
            const int m = q - k;
            if (m >= 0 && m < 64) {
                #pragma unroll
                for (int g = 0; g < 5; ++g) {
                    const int i = f + g * CIN_;
                    sA[m * P_ + i * 3 + k] = (short)f2bf(vals[g]);
                }
            }
        }
    }
    // zero the K padding (kappa = 105..119); B pad is zero too, but LDS
    // garbage could be NaN-patterned and NaN*0 = NaN.
    for (int t = tid; t < 64 * (P_ - K3_); t += 512) {
        const int m = t / (P_ - K3_);
        const int c = K3_ + (t - m * (P_ - K3_));
        sA[m * P_ + c] = 0;
    }
    __syncthreads();

    // ---- Phase 2: MFMA GEMM ----
    const int w  = tid >> 6;          // wave id 0..7 -> d base = w*64
    const int l  = tid & 63;
    const int lr = l & 15;            // A row / C col within 16-tile
    const int lq = l >> 4;            // quad

    float4_ acc[4][4];                // [m-subtile][n-subtile]
    #pragma unroll
    for (int n = 0; n < 4; ++n) {
        const float bv = bias[w * 64 + n * 16 + lr];
        #pragma unroll
        for (int m = 0; m < 4; ++m) acc[m][n] = { bv, bv, bv, bv };
    }

    #pragma unroll
    for (int ks = 0; ks < 4; ++ks) {
        short8 af[4];
        #pragma unroll
        for (int m = 0; m < 4; ++m)   // A[m16+lr][ks*32 + lq*8 ..+7]
            af[m] = *(const short8*)&sA[(m * 16 + lr) * P_ + ks * 32 + lq * 8];

        short8 bf[4];
        #pragma unroll
        for (int n = 0; n < 4; ++n) {
            if (USE_WS) {
                const int nsub = w * 4 + n;
                bf[n] = *(const short8*)(Bf + ((size_t)(nsub * 4 + ks) * 64 + l) * 8);
            } else {
                const int d  = w * 64 + n * 16 + lr;
                const int kb = ks * 32 + lq * 8;
                short8 t8;
                #pragma unroll
                for (int j = 0; j < 8; ++j)
                    t8[j] = (kb + j < K3_) ? (short)f2bf(W[(size_t)d * K3_ + kb + j])
                                           : (short)0;
                bf[n] = t8;
            }
        }

        #pragma unroll
        for (int m = 0; m < 4; ++m)
            #pragma unroll
            for (int n = 0; n < 4; ++n)
                acc[m][n] = __builtin_amdgcn_mfma_f32_16x16x32_bf16(
                    af[m], bf[n], acc[m][n], 0, 0, 0);
    }

    // ---- Epilogue: C/D layout col = lane&15, row = quad*4 + reg ----
    #pragma unroll
    for (int m = 0; m < 4; ++m) {
        #pragma unroll
        for (int n = 0; n < 4; ++n) {
            const int dcol = w * 64 + n * 16 + lr;
            const int row0 = m * 16 + lq * 4;
            float* ob = out + ((size_t)(b * S_ + s0 + row0)) * D_ + dcol;
            #pragma unroll
            for (int r = 0; r < 4; ++r)
                ob[(size_t)r * D_] = acc[m][n][r];
        }
    }
}

// ---------------------------------------------------------------------------
extern "C" void kernel_launch(void* const* d_in, const int* in_sizes, int n_in,
                              void* d_out, int out_size, void* d_ws, size_t ws_size,
                              hipStream_t stream) {
    const float* x      = (const float*)d_in[0];   // (32, 4096, 7)
    // d_in[1] = x_mark: unused by the reference
    const float* W_conv = (const float*)d_in[2];   // (512, 35, 3)
    const float* b_conv = (const float*)d_in[3];   // (512,)
    float* out = (float*)d_out;                    // (32, 4096, 512)

    const size_t bf_bytes = (size_t)32 * 4 * 64 * 8 * sizeof(short);  // 128 KiB

    if (ws_size >= bf_bytes) {
        short* Bf = (short*)d_ws;
        pack_w_kernel<<<dim3(32), dim3(256), 0, stream>>>(W_conv, Bf);
        fused_mfma_kernel<true><<<dim3(S_ / 64, B_), dim3(512), 0, stream>>>(
            x, W_conv, Bf, b_conv, out);
    } else {
        fused_mfma_kernel<false><<<dim3(S_ / 64, B_), dim3(512), 0, stream>>>(
            x, W_conv, nullptr, b_conv, out);
    }
}